// Round 6
// baseline (82.257 us; speedup 1.0000x reference)
//
#include <hip/hip_runtime.h>
#include <hip/hip_bf16.h>

// SparseChannel2Spatial, compacted line-gather version.
// N voxels, C=64 ch, 8 children/voxel, exactly K=4 active -> M = N*4 rows.
// Each 256-thread block owns VPB=64 voxels (16KB feats span):
//   phase A: decode sub masks (1x/voxel); wave-prefix-sum the needed-64B-line
//            counts (line l covers children 2l,2l+1; needed iff either active)
//            into a sorted compacted line list (~3.14 lines/voxel avg).
//   phase B: lanes load the needed lines' 16B quarters in ascending address
//            order (4 contiguous lanes per 64B line -> coalesced holey stream,
//            skips ~21% of feats lines) and scatter active chunks into an
//            output-ordered LDS buffer (inactive sibling chunks -> trash slot).
//   phase C: dense 16B/lane nontemporal stores (same as R5) + coords.
// d_out (float32): [M*8 new_feats][M*4 new_coords-as-float].

typedef float f4 __attribute__((ext_vector_type(4)));
typedef int   i4 __attribute__((ext_vector_type(4)));

#define VPB 64

__global__ __launch_bounds__(256) void sc2s_kernel(
    const float* __restrict__ feats,   // [N, 64]
    const int*   __restrict__ coords,  // [N, 4]
    const int*   __restrict__ sub,     // [N, 8]
    float*       __restrict__ out_feats,   // [M, 8]
    float*       __restrict__ out_coords,  // [M, 4]
    int N) {
  __shared__ int sm[VPB];                          // 8-bit active mask per voxel
  __shared__ int slines[VPB * 4];                  // compacted (vi<<2)|l, sorted
  __shared__ int s_total;                          // number of needed lines
  __shared__ __align__(16) float schunk[(VPB * 8 + 1) * 4];  // 513 x 16B, out-ordered
  __shared__ __align__(16) int sc[VPB * 4];        // coords rows

  int b   = blockIdx.x;
  int tid = threadIdx.x;
  int v0  = b * VPB;

  // ---- phase A: decode + compact needed lines (wave 0), coords (wave 1) ----
  if (tid < VPB) {
    const i4* s4 = reinterpret_cast<const i4*>(sub) + (size_t)(v0 + tid) * 2;
    i4 a = s4[0], bb = s4[1];
    unsigned m = (unsigned)(a.x != 0)
               | ((unsigned)(a.y != 0) << 1)
               | ((unsigned)(a.z != 0) << 2)
               | ((unsigned)(a.w != 0) << 3)
               | ((unsigned)(bb.x != 0) << 4)
               | ((unsigned)(bb.y != 0) << 5)
               | ((unsigned)(bb.z != 0) << 6)
               | ((unsigned)(bb.w != 0) << 7);
    sm[tid] = (int)m;
    // needed 64B lines: line l needed iff children {2l,2l+1} not both inactive
    unsigned lm = (m | (m >> 1)) & 0x55u;          // bits 0,2,4,6
    int lcount = __popc(lm);
    // wave-wide inclusive scan over 64 lanes (tid<64 == wave 0)
    int x = lcount;
    #pragma unroll
    for (int d = 1; d < 64; d <<= 1) {
      int v = __shfl_up(x, d);
      if (tid >= d) x += v;
    }
    int base = x - lcount;
    if (tid == VPB - 1) s_total = x;
    int o = base;
    #pragma unroll
    for (int l = 0; l < 4; ++l) {
      if ((m >> (2 * l)) & 3u) slines[o++] = (tid << 2) | l;
    }
  } else if (tid < 2 * VPB) {
    int vi = tid - VPB;
    reinterpret_cast<i4*>(sc)[vi] = reinterpret_cast<const i4*>(coords)[v0 + vi];
  }
  __syncthreads();

  // ---- phase B: coalesced holey-stream gather of needed lines ----
  int L4 = s_total * 4;                            // 16B quarters to load (512..1024)
  #pragma unroll
  for (int p = 0; p < 4; ++p) {
    int idx = tid + p * 256;
    if (p < 2 || idx < L4) {                       // L4 >= 512 always (>=2 lines/voxel)
      int e     = slines[idx >> 2];
      int vi    = e >> 2;
      int l     = e & 3;
      int q     = idx & 3;                         // quarter within the 64B line
      int child = l * 2 + (q >> 1);
      int half  = q & 1;
      f4 v = reinterpret_cast<const f4*>(feats)[(size_t)(v0 + vi) * 16 + child * 2 + half];
      unsigned m = (unsigned)sm[vi];
      int active = (m >> child) & 1;
      int rank   = __popc(m & ((1u << child) - 1u));
      int cc     = active ? (vi * 8 + rank * 2 + half) : (VPB * 8);  // trash slot
      reinterpret_cast<f4*>(schunk)[cc] = v;
    }
  }
  __syncthreads();

  // ---- phase C: dense 16B-chunk NT stores ----
  f4* ofb = reinterpret_cast<f4*>(out_feats) + (size_t)b * (VPB * 8);
  #pragma unroll
  for (int p = 0; p < 2; ++p) {
    int cc = tid + p * 256;
    f4 v = reinterpret_cast<const f4*>(schunk)[cc];
    __builtin_nontemporal_store(v, ofb + cc);
  }
  {
    int cc = tid;                                  // coords chunk: vi=cc>>2, k=cc&3
    int vi = cc >> 2;
    int k  = cc & 3;
    unsigned m = (unsigned)sm[vi];
    #pragma unroll
    for (int q = 0; q < 3; ++q) {
      if (q < k) m &= (m - 1u);
    }
    int j = __ffs(m) - 1;
    const int* c = &sc[vi * 4];
    f4 o;
    o.x = (float)c[0];
    o.y = (float)(c[1] * 2 + (j & 1));
    o.z = (float)(c[2] * 2 + ((j >> 1) & 1));
    o.w = (float)(c[3] * 2 + ((j >> 2) & 1));
    __builtin_nontemporal_store(o, reinterpret_cast<f4*>(out_coords) + (size_t)b * (VPB * 4) + cc);
  }
}

extern "C" void kernel_launch(void* const* d_in, const int* in_sizes, int n_in,
                              void* d_out, int out_size, void* d_ws, size_t ws_size,
                              hipStream_t stream) {
  const float* feats  = (const float*)d_in[0];  // [N, 64] float32
  const int*   coords = (const int*)d_in[1];    // [N, 4] int32
  const int*   sub    = (const int*)d_in[2];    // [N, 8] int32

  // out_size = M*8 + M*4 = 12*M, M = 4*N
  int M = out_size / 12;
  int N = M / 4;
  float* out_feats  = (float*)d_out;
  float* out_coords = (float*)d_out + (size_t)M * 8;

  // N = 1,000,000 = 15625 * 64 -> exact grid.
  int grid = (N + VPB - 1) / VPB;
  sc2s_kernel<<<grid, 256, 0, stream>>>(feats, coords, sub, out_feats, out_coords, N);
}

// Round 7
// 80.125 us; speedup vs baseline: 1.0266x; 1.0266x over previous
//
#include <hip/hip_runtime.h>
#include <hip/hip_bf16.h>

// SparseChannel2Spatial, block-staged streaming version (R5 structure —
// established best; R6's compacted line-gather was neutral because TCC/HBM
// sector granularity is ~128B, making the feats stream effectively
// irreducible: ~493MB total traffic at 6.1 TB/s mixed BW = roofline).
// N voxels, C=64 ch, 8 children/voxel, exactly K=4 active -> M = N*4 rows.
// Each 256-thread block owns VPB=64 voxels:
//   phase 1: stream full feats rows (64 x 256B, coalesced dwordx4) + sub
//            (decoded once/voxel into packed j0..j3) + coords into LDS;
//   phase 2: select child chunks from LDS (row stride padded to 68 floats
//            to rotate banks) and emit dense 16B/lane nontemporal stores.
// d_out (float32): [M*8 new_feats][M*4 new_coords-as-float].

typedef float f4 __attribute__((ext_vector_type(4)));
typedef int   i4 __attribute__((ext_vector_type(4)));

#define VPB 64          // voxels per block
#define ROWP 68         // padded LDS row stride (floats): 64 + 4

__global__ __launch_bounds__(256) void sc2s_kernel(
    const float* __restrict__ feats,   // [N, 64]
    const int*   __restrict__ coords,  // [N, 4]
    const int*   __restrict__ sub,     // [N, 8]
    float*       __restrict__ out_feats,   // [M, 8]
    float*       __restrict__ out_coords,  // [M, 4]
    int N) {
  __shared__ __align__(16) float sf[VPB * ROWP];  // 17408 B
  __shared__ int sj[VPB];                         // packed j0..j3 per voxel
  __shared__ __align__(16) int sc[VPB * 4];       // coords rows

  int b   = blockIdx.x;
  int tid = threadIdx.x;
  int v0  = b * VPB;

  // ---- phase 1: stream inputs into LDS ----
  {
    // feats: thread tid loads 16 consecutive words of voxel vi = tid/4.
    int vi = tid >> 2, w0 = (tid & 3) << 4;
    const f4* src = reinterpret_cast<const f4*>(feats + (size_t)(v0 + vi) * 64 + w0);
    f4* dst = reinterpret_cast<f4*>(&sf[vi * ROWP + w0]);
    #pragma unroll
    for (int q = 0; q < 4; ++q) dst[q] = src[q];
  }
  if (tid < VPB) {
    // sub: decode once per voxel into packed child slots.
    const i4* s4 = reinterpret_cast<const i4*>(sub) + (size_t)(v0 + tid) * 2;
    i4 a = s4[0], bb = s4[1];
    unsigned m = (unsigned)(a.x != 0)
               | ((unsigned)(a.y != 0) << 1)
               | ((unsigned)(a.z != 0) << 2)
               | ((unsigned)(a.w != 0) << 3)
               | ((unsigned)(bb.x != 0) << 4)
               | ((unsigned)(bb.y != 0) << 5)
               | ((unsigned)(bb.z != 0) << 6)
               | ((unsigned)(bb.w != 0) << 7);
    int j0 = __ffs(m) - 1; m &= m - 1;
    int j1 = __ffs(m) - 1; m &= m - 1;
    int j2 = __ffs(m) - 1; m &= m - 1;
    int j3 = __ffs(m) - 1;
    sj[tid] = j0 | (j1 << 8) | (j2 << 16) | (j3 << 24);
  } else if (tid < 2 * VPB) {
    int vi = tid - VPB;
    reinterpret_cast<i4*>(sc)[vi] = reinterpret_cast<const i4*>(coords)[v0 + vi];
  }
  __syncthreads();

  // ---- phase 2: dense 16B-chunk outputs ----
  // feats: 512 chunks per block; chunk cc: vi=cc>>3, k=(cc>>1)&3, half=cc&1.
  f4* ofb = reinterpret_cast<f4*>(out_feats) + (size_t)b * (VPB * 8);
  #pragma unroll
  for (int p = 0; p < 2; ++p) {
    int cc   = tid + p * 256;
    int vi   = cc >> 3;
    int k    = (cc >> 1) & 3;
    int half = cc & 1;
    int j    = (sj[vi] >> (k * 8)) & 0xff;
    f4 v = *reinterpret_cast<const f4*>(&sf[vi * ROWP + j * 8 + half * 4]);
    __builtin_nontemporal_store(v, ofb + cc);
  }
  // coords: 256 chunks per block; chunk cc: vi=cc>>2, k=cc&3.
  {
    int cc = tid;
    int vi = cc >> 2;
    int k  = cc & 3;
    int j  = (sj[vi] >> (k * 8)) & 0xff;
    const int* c = &sc[vi * 4];
    f4 o;
    o.x = (float)c[0];
    o.y = (float)(c[1] * 2 + (j & 1));
    o.z = (float)(c[2] * 2 + ((j >> 1) & 1));
    o.w = (float)(c[3] * 2 + ((j >> 2) & 1));
    __builtin_nontemporal_store(o, reinterpret_cast<f4*>(out_coords) + (size_t)b * (VPB * 4) + cc);
  }
}

extern "C" void kernel_launch(void* const* d_in, const int* in_sizes, int n_in,
                              void* d_out, int out_size, void* d_ws, size_t ws_size,
                              hipStream_t stream) {
  const float* feats  = (const float*)d_in[0];  // [N, 64] float32
  const int*   coords = (const int*)d_in[1];    // [N, 4] int32
  const int*   sub    = (const int*)d_in[2];    // [N, 8] int32

  // out_size = M*8 + M*4 = 12*M, M = 4*N
  int M = out_size / 12;
  int N = M / 4;
  float* out_feats  = (float*)d_out;
  float* out_coords = (float*)d_out + (size_t)M * 8;

  // N = 1,000,000 = 15625 * 64 -> exact grid, no tail handling needed.
  int grid = (N + VPB - 1) / VPB;
  sc2s_kernel<<<grid, 256, 0, stream>>>(feats, coords, sub, out_feats, out_coords, N);
}